// Round 17
// baseline (752.729 us; speedup 1.0000x reference)
//
#include <hip/hip_runtime.h>

#define NB 8
#define N_PER 4096
#define N_SAMPLE 1024
#define KNN 64
#define CIN 64
#define HD 128
#define R2F 0.04f
#define LIST_CAP 384
#define STR 136  // h1 bf16 LDS row stride (shorts)
#define NFPS 8
#define NWK 244
#define GRID (NFPS + NWK)  // 252 blocks, 1 block/CU (LDS-padded) => all resident
#define GCHUNK 136         // even, 244*136 >= 32768
#define NPTS (NB * N_PER)
#define NTASK (NB * N_SAMPLE)
// dynamic LDS pad: ~53.4K static + 41216 dyn > 163840/2 -> 1 block/CU,
// so the 8 FPS blocks own their CUs (no worker LDS/issue contention).
#define LDS_PAD 41216

typedef __attribute__((ext_vector_type(8))) short bf16x8;
typedef __attribute__((ext_vector_type(4))) float f32x4;

__device__ __forceinline__ unsigned short f2bf(float f) {
    const unsigned u = __float_as_uint(f);
    return (unsigned short)((u + 0x7fff + ((u >> 16) & 1)) >> 16);  // RNE
}

// ---- DPP wave64 64-bit max-reduce (lane 63 ends with the max) --------------
template <int CTRL>
__device__ __forceinline__ unsigned long long dpp_shift_u64(unsigned long long k) {
    const unsigned lo = (unsigned)k;
    const unsigned hi = (unsigned)(k >> 32);
    const unsigned olo =
        (unsigned)__builtin_amdgcn_update_dpp(0, (int)lo, CTRL, 0xf, 0xf, false);
    const unsigned ohi =
        (unsigned)__builtin_amdgcn_update_dpp(0, (int)hi, CTRL, 0xf, 0xf, false);
    return ((unsigned long long)ohi << 32) | olo;
}
__device__ __forceinline__ unsigned long long wave_max_u64(unsigned long long k) {
    unsigned long long o;
    o = dpp_shift_u64<0x111>(k); k = o > k ? o : k;  // row_shr:1
    o = dpp_shift_u64<0x112>(k); k = o > k ? o : k;  // row_shr:2
    o = dpp_shift_u64<0x114>(k); k = o > k ? o : k;  // row_shr:4
    o = dpp_shift_u64<0x118>(k); k = o > k ? o : k;  // row_shr:8
    o = dpp_shift_u64<0x142>(k); k = o > k ? o : k;  // row_bcast:15
    o = dpp_shift_u64<0x143>(k); k = o > k ? o : k;  // row_bcast:31
    return k;
}

// ---- DPP wave64 inclusive add-scan (bcast steps need row_mask 0xa/0xc) -----
template <int CTRL, int RMASK>
__device__ __forceinline__ int dpp_add_step(int v) {
    const int o = __builtin_amdgcn_update_dpp(0, v, CTRL, RMASK, 0xf, false);
    return v + o;
}
__device__ __forceinline__ int wave_incl_scan(int v) {
    v = dpp_add_step<0x111, 0xf>(v);
    v = dpp_add_step<0x112, 0xf>(v);
    v = dpp_add_step<0x114, 0xf>(v);
    v = dpp_add_step<0x118, 0xf>(v);
    v = dpp_add_step<0x142, 0xa>(v);
    v = dpp_add_step<0x143, 0xc>(v);
    return v;  // inclusive prefix; lane 63 = wave total
}

union SMem {
    struct {
        float pxyz[N_PER * 3];
        unsigned long long pkey[2][4];
        int lhist[N_SAMPLE];
    } f;
    struct {
        unsigned long long keys[LIST_CAP + 8];
        short h1b[KNN * STR];
        int sel[KNN];
        float pcW[HD];
        float stripmax[4][HD];
        float gx[2 * CIN];
        float gp[8];
        int wtot[4];
        int bcast;
    } m;
};

// ---- fused kernel: 1 block/CU (dyn-LDS padded) -----------------------------
// blocks 0..7: FPS producers on DEDICATED CUs. Winners tracked in SGPRs
// (readfirstlane + wave-uniform (s&7) branch chain — pure SALU, no register
// arrays) and published once per 8 steps: 4 u64 flag stores + 8 lhist writes.
// 7 of 8 per-step barriers drain no global stores at all.
// blocks 8..: g+W2T phase (release-counter guarded), then main-task consumers.
__global__ __launch_bounds__(256, 2) void fused_kernel(
    const float* __restrict__ pos, const float* __restrict__ x,
    const float* __restrict__ W1, const float* __restrict__ b1,
    const float* __restrict__ W2, const float* __restrict__ b2,
    float* __restrict__ g, short* __restrict__ w2t, int* __restrict__ flags,
    unsigned* __restrict__ gdone, float* __restrict__ x_out,
    float* __restrict__ pos_out, float* __restrict__ batch_out) {
    __shared__ SMem sm;
    const int t = threadIdx.x;

    if (blockIdx.x < NFPS) {
        // ================= FPS: one block per cloud (R6 algorithm) ==========
        const int b = blockIdx.x;
        const float* posb = pos + (size_t)b * N_PER * 3;
        float* pxyz = sm.f.pxyz;
        for (int i = t; i < N_PER * 3; i += 256) pxyz[i] = posb[i];
        __syncthreads();

        float rx[16], ry[16], rz[16], mind[16];
#pragma unroll
        for (int k = 0; k < 16; ++k) {
            const int p = t + (k << 8);
            rx[k] = pxyz[p * 3 + 0];
            ry[k] = pxyz[p * 3 + 1];
            rz[k] = pxyz[p * 3 + 2];
            mind[k] = 1e10f;
        }
        int last = 0;
        // winner slots in scalar regs; slot (s&7) gets step s's winner.
        int w0 = 0, w1 = 0, w2 = 0, w3 = 0, w4 = 0, w5 = 0, w6 = 0;

        for (int s = 1; s < N_SAMPLE; ++s) {
            const float* lp3 = pxyz + last * 3;
            const float lx = lp3[0], ly = lp3[1], lz = lp3[2];
            float bv = -1.0f;
            int bi = 0x7fffffff;
#pragma unroll
            for (int k = 0; k < 16; ++k) {
                const float dx = rx[k] - lx;
                const float dy = ry[k] - ly;
                const float dz = rz[k] - lz;
                // exact f32 left-to-right, no FMA contraction
                const float d = __fadd_rn(
                    __fadd_rn(__fmul_rn(dx, dx), __fmul_rn(dy, dy)), __fmul_rn(dz, dz));
                const float m = fminf(mind[k], d);
                mind[k] = m;
                if (m > bv) { bv = m; bi = t + (k << 8); }
            }
            // dists >= 0: (f32 dist, min idx) order == u64 order of (bits, ~idx)
            unsigned long long key =
                ((unsigned long long)__float_as_uint(bv) << 32) | (unsigned)(~bi);
            key = wave_max_u64(key);

            const int par = s & 1;
            if ((t & 63) == 63) sm.f.pkey[par][t >> 6] = key;
            __syncthreads();
            const ulonglong2* pk2 = (const ulonglong2*)(&sm.f.pkey[par][0]);
            const ulonglong2 A = pk2[0], Bq = pk2[1];
            unsigned long long f0 = A.x > A.y ? A.x : A.y;
            const unsigned long long f1 = Bq.x > Bq.y ? Bq.x : Bq.y;
            f0 = f0 > f1 ? f0 : f1;
            last = (int)(~(unsigned)f0);

            // SALU winner bookkeeping (wave-uniform branches, off the VALU path)
            const int ls = __builtin_amdgcn_readfirstlane(last);
            const int ph = s & 7;
            if (ph == 7) {
                // publish steps s-7..s: 4 u64 flag stores + 8 lhist entries
                if (t == ((s >> 3) & 255)) {
                    const int s0 = s - 7;
                    const int gb = b * N_PER + 1;
                    unsigned long long* fl =
                        (unsigned long long*)&flags[b * N_SAMPLE + s0];
                    const unsigned long long v0 =
                        ((unsigned long long)(unsigned)(gb + w1) << 32) |
                        (unsigned)(gb + w0);
                    const unsigned long long v1 =
                        ((unsigned long long)(unsigned)(gb + w3) << 32) |
                        (unsigned)(gb + w2);
                    const unsigned long long v2 =
                        ((unsigned long long)(unsigned)(gb + w5) << 32) |
                        (unsigned)(gb + w4);
                    const unsigned long long v3 =
                        ((unsigned long long)(unsigned)(gb + ls) << 32) |
                        (unsigned)(gb + w6);
                    __hip_atomic_store(fl + 0, v0, __ATOMIC_RELAXED,
                                       __HIP_MEMORY_SCOPE_AGENT);
                    __hip_atomic_store(fl + 1, v1, __ATOMIC_RELAXED,
                                       __HIP_MEMORY_SCOPE_AGENT);
                    __hip_atomic_store(fl + 2, v2, __ATOMIC_RELAXED,
                                       __HIP_MEMORY_SCOPE_AGENT);
                    __hip_atomic_store(fl + 3, v3, __ATOMIC_RELAXED,
                                       __HIP_MEMORY_SCOPE_AGENT);
                    int* lh = sm.f.lhist + s0;
                    lh[0] = w0; lh[1] = w1; lh[2] = w2; lh[3] = w3;
                    lh[4] = w4; lh[5] = w5; lh[6] = w6; lh[7] = ls;
                }
            } else if (ph == 0) { w0 = ls; }
            else if (ph == 1) { w1 = ls; }
            else if (ph == 2) { w2 = ls; }
            else if (ph == 3) { w3 = ls; }
            else if (ph == 4) { w4 = ls; }
            else if (ph == 5) { w5 = ls; }
            else { w6 = ls; }
        }
        __syncthreads();

        // tail: emit pos_out/batch_out in parallel (off the critical path)
        for (int i = t; i < N_SAMPLE; i += 256) {
            const int li = sm.f.lhist[i];
            pos_out[(size_t)(b * N_SAMPLE + i) * 3 + 0] = pxyz[li * 3 + 0];
            pos_out[(size_t)(b * N_SAMPLE + i) * 3 + 1] = pxyz[li * 3 + 1];
            pos_out[(size_t)(b * N_SAMPLE + i) * 3 + 2] = pxyz[li * 3 + 2];
            batch_out[b * N_SAMPLE + i] = (float)b;
        }
        return;
    }

    // ================= workers ==============================================
    const int w = (int)blockIdx.x - NFPS;

    // ---- phase 1: W2T (first 64 workers) + g slice -------------------------
    if (w < 64) {
        const int idx = w * 256 + t;  // = n*128 + k
        w2t[idx] = (short)f2bf(W2[(idx & 127) * HD + (idx >> 7)]);
    }
    {
        const int p0 = w * GCHUNK;
        const int p1 = min(NPTS, p0 + GCHUNK);
        for (int pp = p0; pp < p1; pp += 2) {
            if (t < 2 * CIN && (size_t)pp * CIN + t < (size_t)NPTS * CIN)
                sm.m.gx[t] = x[(size_t)pp * CIN + t];
            if (t < 6 && pp * 3 + t < NPTS * 3) sm.m.gp[t] = pos[pp * 3 + t];
            __syncthreads();
            const int lp = t >> 7;
            const int h = t & 127;
            if (pp + lp < p1) {
                float acc = b1[h];
                const float* xv = sm.m.gx + lp * CIN;
#pragma unroll 8
                for (int c = 0; c < CIN; ++c) acc += xv[c] * W1[c * HD + h];
                const float* pv = sm.m.gp + lp * 3;
#pragma unroll
                for (int d = 0; d < 3; ++d) acc += pv[d] * W1[(CIN + d) * HD + h];
                g[(size_t)(pp + lp) * HD + h] = acc;
            }
            __syncthreads();
        }
    }
    __threadfence();  // make this thread's g/w2t stores device-visible
    __syncthreads();
    if (t == 0)
        __hip_atomic_fetch_add(gdone, 1u, __ATOMIC_RELEASE, __HIP_MEMORY_SCOPE_AGENT);
    if (t == 0) {
        while (__hip_atomic_load(gdone, __ATOMIC_ACQUIRE, __HIP_MEMORY_SCOPE_AGENT) <
               (unsigned)NWK)
            __builtin_amdgcn_s_sleep(32);
    }
    __syncthreads();

    // ---- phase 2: main tasks, ordered by sample index ----------------------
    const int lane = t & 63;
    const int wv = t >> 6;
    for (int j = w; j < NTASK; j += NWK) {
        const int i = j >> 3;  // sample index (production order)
        const int b = j & 7;   // cloud
        const int sidx = b * N_SAMPLE + i;
        if (t == 0) {
            int v;
            while ((unsigned)((v = __hip_atomic_load(&flags[sidx], __ATOMIC_RELAXED,
                                                     __HIP_MEMORY_SCOPE_AGENT)) -
                              1) >= (unsigned)NPTS)
                __builtin_amdgcn_s_sleep(32);
            sm.m.bcast = v - 1;
        }
        if (t < KNN) sm.m.sel[t] = 0;  // defensive in-bounds gather
        __syncthreads();
        const int gci = sm.m.bcast;
        const float cx = pos[(size_t)gci * 3 + 0];  // wave-uniform broadcast loads
        const float cy = pos[(size_t)gci * 3 + 1];
        const float cz = pos[(size_t)gci * 3 + 2];
        if (t < HD) {
            sm.m.pcW[t] = cx * W1[CIN * HD + t] + cy * W1[(CIN + 1) * HD + t] +
                          cz * W1[(CIN + 2) * HD + t];
        }
        const size_t base = (size_t)b * N_PER;

        // ball query pass 1: distances in regs, count hits
        float d2r[16];
        int nh = 0;
#pragma unroll
        for (int k = 0; k < 16; ++k) {
            const int p = t + (k << 8);
            const float* pp = pos + (base + p) * 3;
            const float dx = pp[0] - cx;
            const float dy = pp[1] - cy;
            const float dz = pp[2] - cz;
            const float d2 = __fadd_rn(
                __fadd_rn(__fmul_rn(dx, dx), __fmul_rn(dy, dy)), __fmul_rn(dz, dz));
            d2r[k] = d2;
            nh += (d2 <= R2F) ? 1 : 0;
        }
        const int incl = wave_incl_scan(nh);
        if (lane == 63) sm.m.wtot[wv] = incl;
        __syncthreads();
        const int4 wt = *(const int4*)(&sm.m.wtot[0]);
        const int tot = wt.x + wt.y + wt.z + wt.w;
        int slot = incl - nh;
        if (wv > 0) slot += wt.x;
        if (wv > 1) slot += wt.y;
        if (wv > 2) slot += wt.z;
#pragma unroll
        for (int k = 0; k < 16; ++k) {
            if (d2r[k] <= R2F) {
                if (slot < LIST_CAP)
                    sm.m.keys[slot] =
                        ((unsigned long long)__float_as_uint(d2r[k]) << 32) |
                        (unsigned)(t + (k << 8));
                ++slot;
            }
        }
        const int C = min(tot, LIST_CAP);
        const int Cp = (C + 7) & ~7;
        if (t < Cp - C) sm.m.keys[C + t] = ~0ull;  // sentinels
        __syncthreads();
        const int M = min(C, KNN);

        // exact top-K by rank (lax.top_k tie semantics); x8-unrolled scan
        for (int e = t; e < C; e += 256) {
            const unsigned long long ke = sm.m.keys[e];
            int rank = 0;
            for (int q = 0; q < Cp; q += 8) {
#pragma unroll
                for (int jj = 0; jj < 8; ++jj) rank += (sm.m.keys[q + jj] < ke) ? 1 : 0;
            }
            if (rank < KNN) sm.m.sel[rank] = (int)(ke & 0xFFFFFFFFull);
        }
        __syncthreads();

        // h1[m][h] = relu(g[j_m][h] - pcW[h]) -> bf16 LDS
        for (int lin = t; lin < KNN * (HD / 2); lin += 256) {
            const int m = lin >> 6;
            const int hp = lin & 63;
            float v0 = 0.0f, v1 = 0.0f;
            if (m < M) {
                const float2 gv =
                    *(const float2*)(g + (base + sm.m.sel[m]) * HD + 2 * hp);
                v0 = fmaxf(gv.x - sm.m.pcW[2 * hp], 0.0f);
                v1 = fmaxf(gv.y - sm.m.pcW[2 * hp + 1], 0.0f);
            }
            const unsigned pk = (unsigned)f2bf(v0) | ((unsigned)f2bf(v1) << 16);
            *(unsigned*)(&sm.m.h1b[m * STR + 2 * hp]) = pk;
        }
        __syncthreads();

        // layer 2 MFMA 16x16x32 bf16; wave wv owns m-strip [16wv,16wv+16)
        const int row = lane & 15;
        const int kg = lane >> 4;
        bf16x8 afr[4];
#pragma unroll
        for (int kc = 0; kc < 4; ++kc)
            afr[kc] =
                *(const bf16x8*)(&sm.m.h1b[(wv * 16 + row) * STR + kc * 32 + kg * 8]);

#pragma unroll
        for (int nt = 0; nt < 8; ++nt) {
            f32x4 acc = {0.0f, 0.0f, 0.0f, 0.0f};
#pragma unroll
            for (int kc = 0; kc < 4; ++kc) {
                const bf16x8 bfr =
                    *(const bf16x8*)(w2t + (nt * 16 + row) * HD + kc * 32 + kg * 8);
                acc = __builtin_amdgcn_mfma_f32_16x16x32_bf16(afr[kc], bfr, acc, 0, 0, 0);
            }
            const float bb = b2[nt * 16 + row];
            float mxv = -1e9f;
#pragma unroll
            for (int r = 0; r < 4; ++r) {
                const int m = wv * 16 + kg * 4 + r;
                const float v = fmaxf(acc[r] + bb, 0.0f);
                if (m < M) mxv = fmaxf(mxv, v);
            }
            mxv = fmaxf(mxv, __shfl_xor(mxv, 16));
            mxv = fmaxf(mxv, __shfl_xor(mxv, 32));
            if (lane < 16) sm.m.stripmax[wv][nt * 16 + lane] = mxv;
        }
        __syncthreads();
        if (t < HD) {
            const float v = fmaxf(fmaxf(sm.m.stripmax[0][t], sm.m.stripmax[1][t]),
                                  fmaxf(sm.m.stripmax[2][t], sm.m.stripmax[3][t]));
            x_out[(size_t)sidx * HD + t] = v;
        }
        __syncthreads();  // protect LDS reuse before next task
    }
}

extern "C" void kernel_launch(void* const* d_in, const int* in_sizes, int n_in,
                              void* d_out, int out_size, void* d_ws, size_t ws_size,
                              hipStream_t stream) {
    const float* x   = (const float*)d_in[0];
    const float* pos = (const float*)d_in[1];
    const float* W1  = (const float*)d_in[2];
    const float* b1  = (const float*)d_in[3];
    const float* W2  = (const float*)d_in[4];
    const float* b2  = (const float*)d_in[5];

    float* out = (float*)d_out;
    float* x_out     = out;                                  // [8192,128]
    float* pos_out   = out + (size_t)NB * N_SAMPLE * HD;     // [8192,3]
    float* batch_out = pos_out + (size_t)NB * N_SAMPLE * 3;  // [8192]

    short*    w2t   = (short*)d_ws;                          // [0,32K): bf16 W2T
    int*      flags = (int*)((char*)d_ws + 32768);           // [32K,64K): 8192 flags
    unsigned* gdone = (unsigned*)((char*)d_ws + 65536);      // [64K,+4K): counter
    float*    g     = (float*)((char*)d_ws + 69632);         // [68K,+16M): g

    // flags need no init: 0xAA poison decodes as "not ready" and producers
    // overwrite every slot. Only the g-phase counter needs a true zero.
    hipMemsetAsync(gdone, 0, 4, stream);

    // LDS_PAD forces 1 block/CU so FPS blocks run on dedicated CUs.
    fused_kernel<<<GRID, 256, LDS_PAD, stream>>>(pos, x, W1, b1, W2, b2, g, w2t,
                                                 flags, gdone, x_out, pos_out,
                                                 batch_out);
}

// Round 18
// 713.652 us; speedup vs baseline: 1.0548x; 1.0548x over previous
//
#include <hip/hip_runtime.h>

#define NB 8
#define N_PER 4096
#define N_SAMPLE 1024
#define KNN 64
#define CIN 64
#define HD 128
#define R2F 0.04f
#define LIST_CAP 384
#define STR 136  // h1 bf16 LDS row stride (shorts)
#define NFPS 8
#define NWK 244
#define GRID (NFPS + NWK)  // 252 blocks, 1 block/CU (LDS-padded) => all resident
#define GCHUNK 136         // even, 244*136 >= 32768
#define NPTS (NB * N_PER)
#define NTASK (NB * N_SAMPLE)
// dynamic LDS pad: ~53.4K static + 41216 dyn > 163840/2 -> 1 block/CU,
// so the 8 FPS blocks own their CUs (no worker LDS/issue contention).
#define LDS_PAD 41216

typedef __attribute__((ext_vector_type(8))) short bf16x8;
typedef __attribute__((ext_vector_type(4))) float f32x4;

__device__ __forceinline__ unsigned short f2bf(float f) {
    const unsigned u = __float_as_uint(f);
    return (unsigned short)((u + 0x7fff + ((u >> 16) & 1)) >> 16);  // RNE
}

// ---- DPP wave64 64-bit max-reduce (lane 63 ends with the max) --------------
template <int CTRL>
__device__ __forceinline__ unsigned long long dpp_shift_u64(unsigned long long k) {
    const unsigned lo = (unsigned)k;
    const unsigned hi = (unsigned)(k >> 32);
    const unsigned olo =
        (unsigned)__builtin_amdgcn_update_dpp(0, (int)lo, CTRL, 0xf, 0xf, false);
    const unsigned ohi =
        (unsigned)__builtin_amdgcn_update_dpp(0, (int)hi, CTRL, 0xf, 0xf, false);
    return ((unsigned long long)ohi << 32) | olo;
}
__device__ __forceinline__ unsigned long long wave_max_u64(unsigned long long k) {
    unsigned long long o;
    o = dpp_shift_u64<0x111>(k); k = o > k ? o : k;  // row_shr:1
    o = dpp_shift_u64<0x112>(k); k = o > k ? o : k;  // row_shr:2
    o = dpp_shift_u64<0x114>(k); k = o > k ? o : k;  // row_shr:4
    o = dpp_shift_u64<0x118>(k); k = o > k ? o : k;  // row_shr:8
    o = dpp_shift_u64<0x142>(k); k = o > k ? o : k;  // row_bcast:15
    o = dpp_shift_u64<0x143>(k); k = o > k ? o : k;  // row_bcast:31
    return k;
}

// ---- DPP wave64 inclusive add-scan (bcast steps need row_mask 0xa/0xc) -----
template <int CTRL, int RMASK>
__device__ __forceinline__ int dpp_add_step(int v) {
    const int o = __builtin_amdgcn_update_dpp(0, v, CTRL, RMASK, 0xf, false);
    return v + o;
}
__device__ __forceinline__ int wave_incl_scan(int v) {
    v = dpp_add_step<0x111, 0xf>(v);
    v = dpp_add_step<0x112, 0xf>(v);
    v = dpp_add_step<0x114, 0xf>(v);
    v = dpp_add_step<0x118, 0xf>(v);
    v = dpp_add_step<0x142, 0xa>(v);
    v = dpp_add_step<0x143, 0xc>(v);
    return v;  // inclusive prefix; lane 63 = wave total
}

union SMem {
    struct {
        float pxyz[N_PER * 3];
        unsigned long long pkey[2][4];
        int lhist[N_SAMPLE];
    } f;
    struct {
        unsigned long long keys[LIST_CAP + 8];
        short h1b[KNN * STR];
        int sel[KNN];
        float pcW[HD];
        float stripmax[4][HD];
        float gx[2 * CIN];
        float gp[8];
        int wtot[4];
        int bcast;
    } m;
};

// ---- fused kernel: 1 block/CU (dyn-LDS padded) -----------------------------
// blocks 0..7: FPS producers on DEDICATED CUs. Flags published as one u64
// per 2 steps (scalar wprev/last regs — no register arrays); pos_out/batch_out
// deferred to an lhist tail so the per-step barrier drains almost nothing.
// blocks 8..: g+W2T phase (release-counter guarded), then main-task consumers.
__global__ __launch_bounds__(256, 2) void fused_kernel(
    const float* __restrict__ pos, const float* __restrict__ x,
    const float* __restrict__ W1, const float* __restrict__ b1,
    const float* __restrict__ W2, const float* __restrict__ b2,
    float* __restrict__ g, short* __restrict__ w2t, int* __restrict__ flags,
    unsigned* __restrict__ gdone, float* __restrict__ x_out,
    float* __restrict__ pos_out, float* __restrict__ batch_out) {
    __shared__ SMem sm;
    const int t = threadIdx.x;

    if (blockIdx.x < NFPS) {
        // ================= FPS: one block per cloud (R6 algorithm) ==========
        const int b = blockIdx.x;
        const float* posb = pos + (size_t)b * N_PER * 3;
        float* pxyz = sm.f.pxyz;
        for (int i = t; i < N_PER * 3; i += 256) pxyz[i] = posb[i];
        if (t == 0) sm.f.lhist[0] = 0;
        __syncthreads();

        float rx[16], ry[16], rz[16], mind[16];
#pragma unroll
        for (int k = 0; k < 16; ++k) {
            const int p = t + (k << 8);
            rx[k] = pxyz[p * 3 + 0];
            ry[k] = pxyz[p * 3 + 1];
            rz[k] = pxyz[p * 3 + 2];
            mind[k] = 1e10f;
        }
        int last = 0;
        int wprev = 0;  // winner of the previous (even) step; step 0 winner = 0

        for (int s = 1; s < N_SAMPLE; ++s) {
            const float* lp3 = pxyz + last * 3;
            const float lx = lp3[0], ly = lp3[1], lz = lp3[2];
            float bv = -1.0f;
            int bi = 0x7fffffff;
#pragma unroll
            for (int k = 0; k < 16; ++k) {
                const float dx = rx[k] - lx;
                const float dy = ry[k] - ly;
                const float dz = rz[k] - lz;
                // exact f32 left-to-right, no FMA contraction
                const float d = __fadd_rn(
                    __fadd_rn(__fmul_rn(dx, dx), __fmul_rn(dy, dy)), __fmul_rn(dz, dz));
                const float m = fminf(mind[k], d);
                mind[k] = m;
                if (m > bv) { bv = m; bi = t + (k << 8); }
            }
            // dists >= 0: (f32 dist, min idx) order == u64 order of (bits, ~idx)
            unsigned long long key =
                ((unsigned long long)__float_as_uint(bv) << 32) | (unsigned)(~bi);
            key = wave_max_u64(key);

            const int par = s & 1;
            if ((t & 63) == 63) sm.f.pkey[par][t >> 6] = key;
            __syncthreads();
            const ulonglong2* pk2 = (const ulonglong2*)(&sm.f.pkey[par][0]);
            const ulonglong2 A = pk2[0], Bq = pk2[1];
            unsigned long long f0 = A.x > A.y ? A.x : A.y;
            const unsigned long long f1 = Bq.x > Bq.y ? Bq.x : Bq.y;
            f0 = f0 > f1 ? f0 : f1;
            last = (int)(~(unsigned)f0);
            if (t == (s & 255)) sm.f.lhist[s] = last;  // tail emits pos/batch

            if (s & 1) {
                // publish winners of steps (s-1, s) as one aligned u64
                if (t == ((s >> 1) & 255)) {
                    const unsigned long long v =
                        ((unsigned long long)(unsigned)(b * N_PER + last + 1) << 32) |
                        (unsigned)(b * N_PER + wprev + 1);
                    __hip_atomic_store(
                        (unsigned long long*)&flags[b * N_SAMPLE + s - 1], v,
                        __ATOMIC_RELAXED, __HIP_MEMORY_SCOPE_AGENT);
                }
            } else {
                wprev = last;
            }
        }
        __syncthreads();

        // tail: emit pos_out/batch_out in parallel (off the critical path)
        for (int i = t; i < N_SAMPLE; i += 256) {
            const int li = sm.f.lhist[i];
            pos_out[(size_t)(b * N_SAMPLE + i) * 3 + 0] = pxyz[li * 3 + 0];
            pos_out[(size_t)(b * N_SAMPLE + i) * 3 + 1] = pxyz[li * 3 + 1];
            pos_out[(size_t)(b * N_SAMPLE + i) * 3 + 2] = pxyz[li * 3 + 2];
            batch_out[b * N_SAMPLE + i] = (float)b;
        }
        return;
    }

    // ================= workers ==============================================
    const int w = (int)blockIdx.x - NFPS;

    // ---- phase 1: W2T (first 64 workers) + g slice -------------------------
    if (w < 64) {
        const int idx = w * 256 + t;  // = n*128 + k
        w2t[idx] = (short)f2bf(W2[(idx & 127) * HD + (idx >> 7)]);
    }
    {
        const int p0 = w * GCHUNK;
        const int p1 = min(NPTS, p0 + GCHUNK);
        for (int pp = p0; pp < p1; pp += 2) {
            if (t < 2 * CIN && (size_t)pp * CIN + t < (size_t)NPTS * CIN)
                sm.m.gx[t] = x[(size_t)pp * CIN + t];
            if (t < 6 && pp * 3 + t < NPTS * 3) sm.m.gp[t] = pos[pp * 3 + t];
            __syncthreads();
            const int lp = t >> 7;
            const int h = t & 127;
            if (pp + lp < p1) {
                float acc = b1[h];
                const float* xv = sm.m.gx + lp * CIN;
#pragma unroll 8
                for (int c = 0; c < CIN; ++c) acc += xv[c] * W1[c * HD + h];
                const float* pv = sm.m.gp + lp * 3;
#pragma unroll
                for (int d = 0; d < 3; ++d) acc += pv[d] * W1[(CIN + d) * HD + h];
                g[(size_t)(pp + lp) * HD + h] = acc;
            }
            __syncthreads();
        }
    }
    __threadfence();  // make this thread's g/w2t stores device-visible
    __syncthreads();
    if (t == 0)
        __hip_atomic_fetch_add(gdone, 1u, __ATOMIC_RELEASE, __HIP_MEMORY_SCOPE_AGENT);
    if (t == 0) {
        while (__hip_atomic_load(gdone, __ATOMIC_ACQUIRE, __HIP_MEMORY_SCOPE_AGENT) <
               (unsigned)NWK)
            __builtin_amdgcn_s_sleep(32);
    }
    __syncthreads();

    // ---- phase 2: main tasks, ordered by sample index ----------------------
    const int lane = t & 63;
    const int wv = t >> 6;
    for (int j = w; j < NTASK; j += NWK) {
        const int i = j >> 3;  // sample index (production order)
        const int b = j & 7;   // cloud
        const int sidx = b * N_SAMPLE + i;
        if (t == 0) {
            int v;
            while ((unsigned)((v = __hip_atomic_load(&flags[sidx], __ATOMIC_RELAXED,
                                                     __HIP_MEMORY_SCOPE_AGENT)) -
                              1) >= (unsigned)NPTS)
                __builtin_amdgcn_s_sleep(32);
            sm.m.bcast = v - 1;
        }
        if (t < KNN) sm.m.sel[t] = 0;  // defensive in-bounds gather
        __syncthreads();
        const int gci = sm.m.bcast;
        const float cx = pos[(size_t)gci * 3 + 0];  // wave-uniform broadcast loads
        const float cy = pos[(size_t)gci * 3 + 1];
        const float cz = pos[(size_t)gci * 3 + 2];
        if (t < HD) {
            sm.m.pcW[t] = cx * W1[CIN * HD + t] + cy * W1[(CIN + 1) * HD + t] +
                          cz * W1[(CIN + 2) * HD + t];
        }
        const size_t base = (size_t)b * N_PER;

        // ball query pass 1: distances in regs, count hits
        float d2r[16];
        int nh = 0;
#pragma unroll
        for (int k = 0; k < 16; ++k) {
            const int p = t + (k << 8);
            const float* pp = pos + (base + p) * 3;
            const float dx = pp[0] - cx;
            const float dy = pp[1] - cy;
            const float dz = pp[2] - cz;
            const float d2 = __fadd_rn(
                __fadd_rn(__fmul_rn(dx, dx), __fmul_rn(dy, dy)), __fmul_rn(dz, dz));
            d2r[k] = d2;
            nh += (d2 <= R2F) ? 1 : 0;
        }
        const int incl = wave_incl_scan(nh);
        if (lane == 63) sm.m.wtot[wv] = incl;
        __syncthreads();
        const int4 wt = *(const int4*)(&sm.m.wtot[0]);
        const int tot = wt.x + wt.y + wt.z + wt.w;
        int slot = incl - nh;
        if (wv > 0) slot += wt.x;
        if (wv > 1) slot += wt.y;
        if (wv > 2) slot += wt.z;
#pragma unroll
        for (int k = 0; k < 16; ++k) {
            if (d2r[k] <= R2F) {
                if (slot < LIST_CAP)
                    sm.m.keys[slot] =
                        ((unsigned long long)__float_as_uint(d2r[k]) << 32) |
                        (unsigned)(t + (k << 8));
                ++slot;
            }
        }
        const int C = min(tot, LIST_CAP);
        const int Cp = (C + 7) & ~7;
        if (t < Cp - C) sm.m.keys[C + t] = ~0ull;  // sentinels
        __syncthreads();
        const int M = min(C, KNN);

        // exact top-K by rank (lax.top_k tie semantics); x8-unrolled scan
        for (int e = t; e < C; e += 256) {
            const unsigned long long ke = sm.m.keys[e];
            int rank = 0;
            for (int q = 0; q < Cp; q += 8) {
#pragma unroll
                for (int jj = 0; jj < 8; ++jj) rank += (sm.m.keys[q + jj] < ke) ? 1 : 0;
            }
            if (rank < KNN) sm.m.sel[rank] = (int)(ke & 0xFFFFFFFFull);
        }
        __syncthreads();

        // h1[m][h] = relu(g[j_m][h] - pcW[h]) -> bf16 LDS
        for (int lin = t; lin < KNN * (HD / 2); lin += 256) {
            const int m = lin >> 6;
            const int hp = lin & 63;
            float v0 = 0.0f, v1 = 0.0f;
            if (m < M) {
                const float2 gv =
                    *(const float2*)(g + (base + sm.m.sel[m]) * HD + 2 * hp);
                v0 = fmaxf(gv.x - sm.m.pcW[2 * hp], 0.0f);
                v1 = fmaxf(gv.y - sm.m.pcW[2 * hp + 1], 0.0f);
            }
            const unsigned pk = (unsigned)f2bf(v0) | ((unsigned)f2bf(v1) << 16);
            *(unsigned*)(&sm.m.h1b[m * STR + 2 * hp]) = pk;
        }
        __syncthreads();

        // layer 2 MFMA 16x16x32 bf16; wave wv owns m-strip [16wv,16wv+16)
        const int row = lane & 15;
        const int kg = lane >> 4;
        bf16x8 afr[4];
#pragma unroll
        for (int kc = 0; kc < 4; ++kc)
            afr[kc] =
                *(const bf16x8*)(&sm.m.h1b[(wv * 16 + row) * STR + kc * 32 + kg * 8]);

#pragma unroll
        for (int nt = 0; nt < 8; ++nt) {
            f32x4 acc = {0.0f, 0.0f, 0.0f, 0.0f};
#pragma unroll
            for (int kc = 0; kc < 4; ++kc) {
                const bf16x8 bfr =
                    *(const bf16x8*)(w2t + (nt * 16 + row) * HD + kc * 32 + kg * 8);
                acc = __builtin_amdgcn_mfma_f32_16x16x32_bf16(afr[kc], bfr, acc, 0, 0, 0);
            }
            const float bb = b2[nt * 16 + row];
            float mxv = -1e9f;
#pragma unroll
            for (int r = 0; r < 4; ++r) {
                const int m = wv * 16 + kg * 4 + r;
                const float v = fmaxf(acc[r] + bb, 0.0f);
                if (m < M) mxv = fmaxf(mxv, v);
            }
            mxv = fmaxf(mxv, __shfl_xor(mxv, 16));
            mxv = fmaxf(mxv, __shfl_xor(mxv, 32));
            if (lane < 16) sm.m.stripmax[wv][nt * 16 + lane] = mxv;
        }
        __syncthreads();
        if (t < HD) {
            const float v = fmaxf(fmaxf(sm.m.stripmax[0][t], sm.m.stripmax[1][t]),
                                  fmaxf(sm.m.stripmax[2][t], sm.m.stripmax[3][t]));
            x_out[(size_t)sidx * HD + t] = v;
        }
        __syncthreads();  // protect LDS reuse before next task
    }
}

extern "C" void kernel_launch(void* const* d_in, const int* in_sizes, int n_in,
                              void* d_out, int out_size, void* d_ws, size_t ws_size,
                              hipStream_t stream) {
    const float* x   = (const float*)d_in[0];
    const float* pos = (const float*)d_in[1];
    const float* W1  = (const float*)d_in[2];
    const float* b1  = (const float*)d_in[3];
    const float* W2  = (const float*)d_in[4];
    const float* b2  = (const float*)d_in[5];

    float* out = (float*)d_out;
    float* x_out     = out;                                  // [8192,128]
    float* pos_out   = out + (size_t)NB * N_SAMPLE * HD;     // [8192,3]
    float* batch_out = pos_out + (size_t)NB * N_SAMPLE * 3;  // [8192]

    short*    w2t   = (short*)d_ws;                          // [0,32K): bf16 W2T
    int*      flags = (int*)((char*)d_ws + 32768);           // [32K,64K): 8192 flags
    unsigned* gdone = (unsigned*)((char*)d_ws + 65536);      // [64K,+4K): counter
    float*    g     = (float*)((char*)d_ws + 69632);         // [68K,+16M): g

    // flags need no init: 0xAA poison decodes as "not ready" and producers
    // overwrite every slot. Only the g-phase counter needs a true zero.
    hipMemsetAsync(gdone, 0, 4, stream);

    // LDS_PAD forces 1 block/CU so FPS blocks run on dedicated CUs.
    fused_kernel<<<GRID, 256, LDS_PAD, stream>>>(pos, x, W1, b1, W2, b2, g, w2t,
                                                 flags, gdone, x_out, pos_out,
                                                 batch_out);
}